// Round 7
// baseline (96.527 us; speedup 1.0000x reference)
//
#include <hip/hip_runtime.h>
#include <stdint.h>

#define GXD 512
#define GYD 512
#define NCELL (GXD*GYD)          // 262144 (GZ=1)
#define NB 4
#define NPTS 200000
#define MAXVOX 20000
#define MAXPTS 30

#define CELLS_PER_BLOCK 2048
#define NSCAN_BLOCKS ((NB*NCELL)/CELLS_PER_BLOCK)   // 512 windows, 128 per batch
#define LIN_INVALID 0x7FFFFu

typedef __attribute__((ext_vector_type(4))) float floatx4;

static __device__ __forceinline__ void nt_store4(float* dst, float a, float b, float c, float d) {
    floatx4 v = {a, b, c, d};
    __builtin_nontemporal_store(v, reinterpret_cast<floatx4*>(dst));
}
static __device__ __forceinline__ void nt_copy4(float* dst, const float4& p) {
    floatx4 v = {p.x, p.y, p.z, p.w};
    __builtin_nontemporal_store(v, reinterpret_cast<floatx4*>(dst));
}

// ---------------- K0: zero counts (4 MB) + ticket ----------------
__global__ void zero_counts_kernel(uint4* __restrict__ p, int n4) {
    int g = blockIdx.x * 256 + threadIdx.x;
    if (g < n4) p[g] = make_uint4(0u, 0u, 0u, 0u);
}

// ---------------- K1: bin points; atomicAdd gives arrival slot; pack (slot<<19)|lin ----------------
__global__ void bin_kernel(const float* __restrict__ pts,
                           unsigned int* __restrict__ linslot,
                           int* __restrict__ counts) {
    int g = blockIdx.x * 256 + threadIdx.x;   // grid exactly NB*NPTS/256
    float4 p = reinterpret_cast<const float4*>(pts)[g];
    // exact replication of reference f32 math
    float fx = floorf((p.x - (-51.2f)) / 0.2f);
    float fy = floorf((p.y - (-51.2f)) / 0.2f);
    float fz = floorf((p.z - (-5.0f)) / 8.0f);
    int cx = (int)fx, cy = (int)fy, cz = (int)fz;
    unsigned int rec = 0xFFFFFFFFu;
    if (cx >= 0 && cx < GXD && cy >= 0 && cy < GYD && cz == 0) {
        int lin = cy * GXD + cx;
        int b = g / NPTS;
        int slot = atomicAdd(&counts[b * NCELL + lin], 1);
        rec = ((unsigned int)slot << 19) | (unsigned int)lin;
    }
    linslot[g] = rec;
}

// ---------------- K2: per-window scan + last-block cross-window scan ----------------
// locpfx[cell] = (occ_excl<<18) | cnt_excl (within window)
// last block publishes occoff[512], cntoff[512] (global exclusive per window), used[NB]
__global__ __launch_bounds__(512)
void blockscan_kernel(const int* __restrict__ counts,
                      unsigned int* __restrict__ locpfx,
                      unsigned long long* __restrict__ bsums,
                      unsigned int* __restrict__ ticket,
                      unsigned int* __restrict__ occoff,
                      unsigned int* __restrict__ cntoff,
                      unsigned int* __restrict__ used) {
    int bid = blockIdx.x;
    int tid = threadIdx.x;
    __shared__ unsigned long long s[512];
    __shared__ int islast;
    if (tid == 0) islast = 0;

    int4 c = reinterpret_cast<const int4*>(counts + bid * CELLS_PER_BLOCK)[tid];
    unsigned long long v0 = (unsigned int)c.x | ((unsigned long long)(c.x > 0) << 32);
    unsigned long long v1 = (unsigned int)c.y | ((unsigned long long)(c.y > 0) << 32);
    unsigned long long v2 = (unsigned int)c.z | ((unsigned long long)(c.z > 0) << 32);
    unsigned long long v3 = (unsigned int)c.w | ((unsigned long long)(c.w > 0) << 32);
    unsigned long long i0 = v0, i1 = i0 + v1, i2 = i1 + v2, i3 = i2 + v3;
    s[tid] = i3;
    __syncthreads();
    for (int off = 1; off < 512; off <<= 1) {
        unsigned long long a = (tid >= off) ? s[tid - off] : 0ull;
        __syncthreads();
        s[tid] += a;
        __syncthreads();
    }
    unsigned long long e = s[tid] - i3;
    uint4 o;
    o.x = ((unsigned int)(e >> 32) << 18) | (unsigned int)(e & 0x3FFFFull);
    e += v0; o.y = ((unsigned int)(e >> 32) << 18) | (unsigned int)(e & 0x3FFFFull);
    e += v1; o.z = ((unsigned int)(e >> 32) << 18) | (unsigned int)(e & 0x3FFFFull);
    e += v2; o.w = ((unsigned int)(e >> 32) << 18) | (unsigned int)(e & 0x3FFFFull);
    reinterpret_cast<uint4*>(locpfx + bid * CELLS_PER_BLOCK)[tid] = o;

    if (tid == 511) {
        bsums[bid] = s[511];
        __threadfence();                       // release: make bsums visible device-wide
        unsigned int old = atomicAdd(ticket, 1u);
        islast = (old == NSCAN_BLOCKS - 1);
    }
    __syncthreads();
    if (islast) {
        __threadfence();                       // acquire: see all blocks' bsums
        unsigned long long v = bsums[tid];
        s[tid] = v;
        __syncthreads();
        for (int off = 1; off < 128; off <<= 1) {
            unsigned long long a = ((tid & 127) >= off) ? s[tid - off] : 0ull;
            __syncthreads();
            s[tid] += a;
            __syncthreads();
        }
        unsigned long long ex = s[tid] - v;
        occoff[tid] = (unsigned int)(ex >> 32);
        cntoff[tid] = (unsigned int)ex;
        if ((tid & 127) == 127) {
            unsigned int tot = (unsigned int)(s[tid] >> 32);
            used[tid >> 7] = tot < MAXVOX ? tot : MAXVOX;
        }
    }
}

// ---------------- K3: scatter + (blocks 0..511) desc emit — no scan prelude ----------------
__global__ __launch_bounds__(512)
void scatter_desc_kernel(const unsigned int* __restrict__ linslot,
                         const int* __restrict__ counts,
                         const unsigned int* __restrict__ locpfx,
                         const unsigned int* __restrict__ occoff,
                         const unsigned int* __restrict__ cntoff,
                         int* __restrict__ order_buf,
                         uint4* __restrict__ voxinfo) {
    int tid = threadIdx.x;
    int bid = blockIdx.x;

    // desc: window bid emits voxinfo rows for its occupied cells with gid < MAXVOX
    if (bid < NSCAN_BLOCKS) {
        unsigned int gidbase = occoff[bid];
        if (gidbase < MAXVOX) {
            int b = bid >> 7;
            unsigned int cbase = cntoff[bid];
            int4 c = reinterpret_cast<const int4*>(counts + bid * CELLS_PER_BLOCK)[tid];
            uint4 lp4 = reinterpret_cast<const uint4*>(locpfx + bid * CELLS_PER_BLOCK)[tid];
            int cellbase = (bid & 127) * CELLS_PER_BLOCK + tid * 4;
            int cnts[4] = {c.x, c.y, c.z, c.w};
            unsigned int lps[4] = {lp4.x, lp4.y, lp4.z, lp4.w};
            #pragma unroll
            for (int k = 0; k < 4; ++k) {
                int cnt = cnts[k];
                if (cnt == 0) continue;
                unsigned int gid = gidbase + (lps[k] >> 18);
                if (gid >= MAXVOX) continue;
                unsigned int start = cbase + (lps[k] & 0x3FFFFu);
                voxinfo[b * MAXVOX + gid] =
                    make_uint4((unsigned int)(cellbase + k), start, (unsigned int)cnt, 0u);
            }
        }
    }

    // scatter
    int g = bid * 512 + tid;
    if (g < NB * NPTS) {
        unsigned int rec = linslot[g];
        unsigned int lin = rec & 0x7FFFFu;
        if (lin != LIN_INVALID) {
            int slot = (int)(rec >> 19);
            int b = g / NPTS;
            int gcell = b * NCELL + (int)lin;
            unsigned int lp = locpfx[gcell];
            int start = (int)cntoff[gcell >> 11] + (int)(lp & 0x3FFFFu);
            order_buf[(size_t)b * NPTS + start + slot] = g - b * NPTS;
        }
    }
}

// ---------------- K4: emit — 32 lanes per output row, non-temporal output stores ----------------
__global__ __launch_bounds__(256)
void emit_kernel(const uint4* __restrict__ voxinfo,
                 const unsigned int* __restrict__ used,
                 const int* __restrict__ order_buf,
                 const float* __restrict__ pts,
                 float* __restrict__ out_vox,
                 float* __restrict__ out_coors,
                 float* __restrict__ out_cnt) {
    int gt = blockIdx.x * 256 + threadIdx.x;
    int row = gt >> 5;            // grid sized exactly: NB*MAXVOX rows
    int lane = gt & 31;
    int b = row / MAXVOX;
    int gid = row - b * MAXVOX;
    float* vox = out_vox + (size_t)row * (MAXPTS * 4);

    if ((unsigned int)gid >= used[b]) {
        if (lane < MAXPTS) nt_store4(vox + lane * 4, 0.f, 0.f, 0.f, 0.f);
        else if (lane == 30) nt_store4(out_coors + row * 4, (float)b, -1.f, -1.f, -1.f);
        else __builtin_nontemporal_store(0.f, &out_cnt[row]);
        return;
    }

    uint4 vi = voxinfo[row];
    int cell = (int)vi.x;
    int start = (int)vi.y;
    int cnt = (int)vi.z;
    int kept = cnt < MAXPTS ? cnt : MAXPTS;
    const int* seg = order_buf + (size_t)b * NPTS + start;

    if (lane < MAXPTS && lane >= kept) nt_store4(vox + lane * 4, 0.f, 0.f, 0.f, 0.f);
    for (int jj = lane; jj < cnt; jj += 32) {                   // rank-select points
        int vidx = seg[jj];
        int rank = 0;
        for (int i = 0; i < cnt; ++i) rank += (seg[i] < vidx);
        if (rank < MAXPTS) {
            float4 p = reinterpret_cast<const float4*>(pts)[(size_t)b * NPTS + vidx];
            nt_copy4(vox + rank * 4, p);
        }
    }
    if (lane == 30)
        nt_store4(out_coors + row * 4,
                  (float)b, 0.f, (float)(cell >> 9), (float)(cell & (GXD - 1)));
    if (lane == 31) __builtin_nontemporal_store((float)kept, &out_cnt[row]);
}

extern "C" void kernel_launch(void* const* d_in, const int* in_sizes, int n_in,
                              void* d_out, int out_size, void* d_ws, size_t ws_size,
                              hipStream_t stream) {
    (void)in_sizes; (void)n_in; (void)ws_size; (void)out_size;
    const float* pts = (const float*)d_in[0];
    float* out = (float*)d_out;

    float* out_vox   = out;
    float* out_coors = out + (size_t)NB * MAXVOX * MAXPTS * 4;
    float* out_cnt   = out_coors + (size_t)NB * MAXVOX * 4;

    char* w = (char*)d_ws;
    int* counts = (int*)w;                     w += (size_t)NB * NCELL * 4;        // 4 MB
    unsigned int* ticket = (unsigned int*)w;   w += 16;                            // zeroed with counts
    unsigned int* linslot = (unsigned int*)w;  w += (size_t)NB * NPTS * 4;         // 3.2 MB
    unsigned int* locpfx = (unsigned int*)w;   w += (size_t)NB * NCELL * 4;        // 4 MB
    unsigned long long* bsums = (unsigned long long*)w; w += (size_t)NSCAN_BLOCKS * 8;
    unsigned int* occoff = (unsigned int*)w;   w += (size_t)NSCAN_BLOCKS * 4;
    unsigned int* cntoff = (unsigned int*)w;   w += (size_t)NSCAN_BLOCKS * 4;
    unsigned int* used = (unsigned int*)w;     w += 16;
    int* order_buf = (int*)w;                  w += (size_t)NB * NPTS * 4;         // 3.2 MB
    uint4* voxinfo = (uint4*)w;                w += (size_t)NB * MAXVOX * 16;      // 1.28 MB

    int n4 = (NB * NCELL * 4 + 16) / 16;       // counts + ticket, in uint4 units
    zero_counts_kernel<<<(n4 + 255) / 256, 256, 0, stream>>>(reinterpret_cast<uint4*>(counts), n4);
    bin_kernel<<<(NB * NPTS) / 256, 256, 0, stream>>>(pts, linslot, counts);
    blockscan_kernel<<<NSCAN_BLOCKS, 512, 0, stream>>>(counts, locpfx, bsums, ticket,
                                                       occoff, cntoff, used);
    scatter_desc_kernel<<<(NB * NPTS + 511) / 512, 512, 0, stream>>>(linslot, counts, locpfx,
                                                                     occoff, cntoff,
                                                                     order_buf, voxinfo);
    emit_kernel<<<(NB * MAXVOX * 32) / 256, 256, 0, stream>>>(voxinfo, used, order_buf, pts,
                                                              out_vox, out_coors, out_cnt);
}